// Round 4
// baseline (4322.271 us; speedup 1.0000x reference)
//
#include <hip/hip_runtime.h>
#include <math.h>

// WaveNet on MI355X — round 4.
// R3 forensics: FETCH 246MB + WRITE 427MB per layer = register spills
// (live set ~240 floats vs compiler's 128-VGPR choice). Fix: TPT=2 far-split
// kept (weight s_load amortized over 64 FMAs) but taps processed one k at a
// time -> live set ~106 floats, no spill. Weights via uniform global pointers
// (compiler scalarizes to s_load; FMA reads the SGPR operand directly).

constexpr int TL = 65536;    // T
constexpr int HALF = 131072; // thread j handles g=j and g=j+HALF (same t, b and b+2)

// ---------------- weight packing ----------------
// conv_w/gate_w [18][o=16][i=16][k=3] -> packed [18][k=3][i=16][o=16]  (o fastest)
// res_w [17][o=16][i=16] -> [17][i=16][o=16]
// layer-0 folded with start_w: e0f[k][o] = sum_i conv_w[0][o][i][k]*start_w[i]
__global__ __launch_bounds__(256) void pack_kernel(
    const float* __restrict__ start_w,
    const float* __restrict__ conv_w,
    const float* __restrict__ gate_w,
    const float* __restrict__ res_w,
    float* __restrict__ wf, float* __restrict__ wg,
    float* __restrict__ rw, float* __restrict__ e0f, float* __restrict__ e0g)
{
    int idx = blockIdx.x * 256 + threadIdx.x;
    if (idx < 13824) {
        int li = idx / 768;
        int r  = idx % 768;
        int k  = r / 256;
        int i  = (r / 16) % 16;
        int o  = r % 16;
        int src = ((li * 16 + o) * 16 + i) * 3 + k;
        wf[idx] = conv_w[src];
        wg[idx] = gate_w[src];
    } else if (idx < 13824 + 4352) {
        int j  = idx - 13824;
        int li = j / 256;
        int r  = j % 256;
        int i  = r / 16;
        int o  = r % 16;
        rw[j] = res_w[(li * 16 + o) * 16 + i];
    } else if (idx < 13824 + 4352 + 96) {
        int j = idx - 13824 - 4352;   // [0,96): 48 for f, 48 for g
        int which = j / 48;
        int r = j % 48;
        int k = r / 16;
        int o = r % 16;
        const float* src = which ? gate_w : conv_w;
        float s = 0.f;
        #pragma unroll
        for (int i = 0; i < 16; ++i) s += src[(o * 16 + i) * 3 + k] * start_w[i];
        (which ? e0g : e0f)[k * 16 + o] = s;
    }
}

__device__ __forceinline__ float softsign_f(float v) {
    return v * __builtin_amdgcn_rcpf(1.0f + fabsf(v));
}

// ---------------- fused layer kernel ----------------
// MODE 0: first layer (x via folded start conv; writes h_out, skip=)
// MODE 1: middle layer (reads h_in, writes h_out, skip+=)
// MODE 2: last layer (reads h_in, no residual, out = skip + contribution)
template <int MODE>
__global__ __launch_bounds__(256, 2) void layer_kernel(
    const float* __restrict__ x,
    const float* __restrict__ start_w,
    const float* __restrict__ h_in,
    float* __restrict__ h_out,
    const float* __restrict__ wf,   // MODE0: e0f[3][16]; else packed [3][16][16]
    const float* __restrict__ cb,
    const float* __restrict__ wg,
    const float* __restrict__ gb,
    const float* __restrict__ rw,   // packed [i][o], MODE 0/1
    const float* __restrict__ rb,
    const float* __restrict__ mx,   // mixer row slice for this layer [16]
    float* __restrict__ skip,
    float* __restrict__ out,
    int d)
{
    const int j = blockIdx.x * 256 + threadIdx.x;   // j in [0, HALF)
    const int t = j & (TL - 1);

    float f0[16], q0[16], f1[16], q1[16];
    #pragma unroll
    for (int o = 0; o < 16; ++o) {
        f0[o] = cb[o];  f1[o] = f0[o];
        q0[o] = gb[o];  q1[o] = q0[o];
    }

    float hcA[16], hcB[16];   // h at tap t (kept for residual)

    if (MODE == 0) {
        float xA2 = x[j];
        float xA1 = (t >= 1) ? x[j - 1] : 0.f;
        float xA0 = (t >= 2) ? x[j - 2] : 0.f;
        float xB2 = x[j + HALF];
        float xB1 = (t >= 1) ? x[j + HALF - 1] : 0.f;
        float xB0 = (t >= 2) ? x[j + HALF - 2] : 0.f;
        float xsA[3] = {xA0, xA1, xA2};
        float xsB[3] = {xB0, xB1, xB2};
        #pragma unroll
        for (int k = 0; k < 3; ++k) {
            const float va = xsA[k], vb = xsB[k];
            #pragma unroll
            for (int o = 0; o < 16; ++o) {
                f0[o] += wf[k * 16 + o] * va;
                f1[o] += wf[k * 16 + o] * vb;
                q0[o] += wg[k * 16 + o] * va;
                q1[o] += wg[k * 16 + o] * vb;
            }
        }
        #pragma unroll
        for (int o = 0; o < 16; ++o) {
            hcA[o] = start_w[o] * xA2;
            hcB[o] = start_w[o] * xB2;
        }
    } else {
        // tap-by-tap: only ONE tap pair (32 floats) live at a time
        #pragma unroll
        for (int k = 0; k < 3; ++k) {
            const int off = (k - 2) * d;
            const bool ok = (t + off) >= 0;
            const float4* pA = (const float4*)(h_in + (size_t)(j + off) * 16);
            const float4* pB = (const float4*)(h_in + ((size_t)(j + HALF + off)) * 16);
            float inA[16], inB[16];
            #pragma unroll
            for (int q = 0; q < 4; ++q) {
                float4 a = ok ? pA[q] : make_float4(0.f, 0.f, 0.f, 0.f);
                float4 b = ok ? pB[q] : make_float4(0.f, 0.f, 0.f, 0.f);
                inA[q * 4 + 0] = a.x; inA[q * 4 + 1] = a.y;
                inA[q * 4 + 2] = a.z; inA[q * 4 + 3] = a.w;
                inB[q * 4 + 0] = b.x; inB[q * 4 + 1] = b.y;
                inB[q * 4 + 2] = b.z; inB[q * 4 + 3] = b.w;
            }
            #pragma unroll
            for (int i = 0; i < 16; ++i) {
                const float va = inA[i], vb = inB[i];
                const float* __restrict__ pw = wf + (k * 16 + i) * 16;
                const float* __restrict__ pg = wg + (k * 16 + i) * 16;
                #pragma unroll
                for (int o = 0; o < 16; ++o) {
                    f0[o] += pw[o] * va;
                    f1[o] += pw[o] * vb;
                    q0[o] += pg[o] * va;
                    q1[o] += pg[o] * vb;
                }
            }
            if (k == 2) {
                #pragma unroll
                for (int i = 0; i < 16; ++i) { hcA[i] = inA[i]; hcB[i] = inB[i]; }
            }
        }
    }

    float zA[16], zB[16];
    #pragma unroll
    for (int o = 0; o < 16; ++o) {
        zA[o] = softsign_f(f0[o]) * softsign_f(q0[o]);
        zB[o] = softsign_f(f1[o]) * softsign_f(q1[o]);
    }

    float sA = 0.f, sB = 0.f;
    #pragma unroll
    for (int o = 0; o < 16; ++o) {
        sA += mx[o] * zA[o];
        sB += mx[o] * zB[o];
    }

    if (MODE == 0) {
        skip[j] = sA;  skip[j + HALF] = sB;
    } else if (MODE == 1) {
        skip[j] += sA; skip[j + HALF] += sB;
    } else {
        out[j] = skip[j] + sA;
        out[j + HALF] = skip[j + HALF] + sB;
    }

    if (MODE != 2) {
        float hnA[16], hnB[16];
        #pragma unroll
        for (int o = 0; o < 16; ++o) {
            hnA[o] = hcA[o] + rb[o];
            hnB[o] = hcB[o] + rb[o];
        }
        #pragma unroll
        for (int i = 0; i < 16; ++i) {
            const float va = zA[i], vb = zB[i];
            const float* __restrict__ pr = rw + i * 16;
            #pragma unroll
            for (int o = 0; o < 16; ++o) {
                hnA[o] += pr[o] * va;
                hnB[o] += pr[o] * vb;
            }
        }
        float4* qA = (float4*)(h_out + (size_t)j * 16);
        float4* qB = (float4*)(h_out + ((size_t)j + HALF) * 16);
        qA[0] = make_float4(hnA[0],  hnA[1],  hnA[2],  hnA[3]);
        qA[1] = make_float4(hnA[4],  hnA[5],  hnA[6],  hnA[7]);
        qA[2] = make_float4(hnA[8],  hnA[9],  hnA[10], hnA[11]);
        qA[3] = make_float4(hnA[12], hnA[13], hnA[14], hnA[15]);
        qB[0] = make_float4(hnB[0],  hnB[1],  hnB[2],  hnB[3]);
        qB[1] = make_float4(hnB[4],  hnB[5],  hnB[6],  hnB[7]);
        qB[2] = make_float4(hnB[8],  hnB[9],  hnB[10], hnB[11]);
        qB[3] = make_float4(hnB[12], hnB[13], hnB[14], hnB[15]);
    }
}

extern "C" void kernel_launch(void* const* d_in, const int* in_sizes, int n_in,
                              void* d_out, int out_size, void* d_ws, size_t ws_size,
                              hipStream_t stream) {
    const float* x       = (const float*)d_in[0];
    const float* start_w = (const float*)d_in[1];
    const float* conv_w  = (const float*)d_in[2];
    const float* conv_b  = (const float*)d_in[3];
    const float* gate_w  = (const float*)d_in[4];
    const float* gate_b  = (const float*)d_in[5];
    const float* res_w   = (const float*)d_in[6];
    const float* res_b   = (const float*)d_in[7];
    const float* mixer_w = (const float*)d_in[8];
    float* out = (float*)d_out;

    // ws layout (floats):
    float* ws  = (float*)d_ws;
    float* wf  = ws;                 // 13824  packed conv weights
    float* wg  = wf + 13824;         // 13824  packed gate weights
    float* rw  = wg + 13824;         // 4352   packed res weights
    float* e0f = rw + 4352;          // 48     layer0 folded conv weights
    float* e0g = e0f + 48;           // 48
    float* hA  = e0g + 48;           // 4194304  h ping
    float* hB  = hA + 4194304;       // 4194304  h pong
    float* skip = hB + 4194304;      // 262144   running mixer accumulation
    (void)ws_size; (void)in_sizes; (void)n_in; (void)out_size;

    pack_kernel<<<72, 256, 0, stream>>>(start_w, conv_w, gate_w, res_w,
                                        wf, wg, rw, e0f, e0g);

    static const int dil[18] = {1,2,4,8,16,32,64,128,256,1,2,4,8,16,32,64,128,256};
    const int nblk = HALF / 256;   // 512 blocks, 2 per CU

    // layer 0 (fused start conv)
    layer_kernel<0><<<nblk, 256, 0, stream>>>(
        x, start_w, nullptr, hA,
        e0f, conv_b, e0g, gate_b,
        rw, res_b, mixer_w, skip, nullptr, 1);

    float* bufs[2] = {hA, hB};
    for (int li = 1; li < 17; ++li) {
        layer_kernel<1><<<nblk, 256, 0, stream>>>(
            nullptr, nullptr, bufs[(li - 1) & 1], bufs[li & 1],
            wf + li * 768, conv_b + li * 16, wg + li * 768, gate_b + li * 16,
            rw + li * 256, res_b + li * 16, mixer_w + li * 16,
            skip, nullptr, dil[li]);
    }

    // layer 17: no residual, writes final out = skip + contribution
    layer_kernel<2><<<nblk, 256, 0, stream>>>(
        nullptr, nullptr, bufs[0], nullptr,
        wf + 17 * 768, conv_b + 17 * 16, wg + 17 * 768, gate_b + 17 * 16,
        nullptr, nullptr, mixer_w + 17 * 16,
        skip, out, dil[17]);
}

// Round 5
// 4243.331 us; speedup vs baseline: 1.0186x; 1.0186x over previous
//
#include <hip/hip_runtime.h>
#include <math.h>

// WaveNet on MI355X — round 5.
// R4 forensics: WRITE_SIZE excess (18.2MB = 131072 thr x ~34 floats) proves
// register spills; compiler chose 96 VGPRs despite launch_bounds(256,2)
// permitting 256 (it only sets a MINIMUM). Fix: pin the allocator with
// amdgpu_waves_per_eu(2,2) -> full 256-VGPR budget, live set ~130 fits.
// Everything else identical to R4 (TPT=2 far-split, tap-by-tap, s_load
// weights amortized 64 FMAs per fetch).

constexpr int TL = 65536;    // T
constexpr int HALF = 131072; // thread j handles g=j and g=j+HALF (same t, b and b+2)

// ---------------- weight packing ----------------
// conv_w/gate_w [18][o=16][i=16][k=3] -> packed [18][k=3][i=16][o=16]  (o fastest)
// res_w [17][o=16][i=16] -> [17][i=16][o=16]
// layer-0 folded with start_w: e0f[k][o] = sum_i conv_w[0][o][i][k]*start_w[i]
__global__ __launch_bounds__(256) void pack_kernel(
    const float* __restrict__ start_w,
    const float* __restrict__ conv_w,
    const float* __restrict__ gate_w,
    const float* __restrict__ res_w,
    float* __restrict__ wf, float* __restrict__ wg,
    float* __restrict__ rw, float* __restrict__ e0f, float* __restrict__ e0g)
{
    int idx = blockIdx.x * 256 + threadIdx.x;
    if (idx < 13824) {
        int li = idx / 768;
        int r  = idx % 768;
        int k  = r / 256;
        int i  = (r / 16) % 16;
        int o  = r % 16;
        int src = ((li * 16 + o) * 16 + i) * 3 + k;
        wf[idx] = conv_w[src];
        wg[idx] = gate_w[src];
    } else if (idx < 13824 + 4352) {
        int j  = idx - 13824;
        int li = j / 256;
        int r  = j % 256;
        int i  = r / 16;
        int o  = r % 16;
        rw[j] = res_w[(li * 16 + o) * 16 + i];
    } else if (idx < 13824 + 4352 + 96) {
        int j = idx - 13824 - 4352;   // [0,96): 48 for f, 48 for g
        int which = j / 48;
        int r = j % 48;
        int k = r / 16;
        int o = r % 16;
        const float* src = which ? gate_w : conv_w;
        float s = 0.f;
        #pragma unroll
        for (int i = 0; i < 16; ++i) s += src[(o * 16 + i) * 3 + k] * start_w[i];
        (which ? e0g : e0f)[k * 16 + o] = s;
    }
}

__device__ __forceinline__ float softsign_f(float v) {
    return v * __builtin_amdgcn_rcpf(1.0f + fabsf(v));
}

// ---------------- fused layer kernel ----------------
// MODE 0: first layer (x via folded start conv; writes h_out, skip=)
// MODE 1: middle layer (reads h_in, writes h_out, skip+=)
// MODE 2: last layer (reads h_in, no residual, out = skip + contribution)
template <int MODE>
__global__ __launch_bounds__(256)
__attribute__((amdgpu_waves_per_eu(2, 2)))
void layer_kernel(
    const float* __restrict__ x,
    const float* __restrict__ start_w,
    const float* __restrict__ h_in,
    float* __restrict__ h_out,
    const float* __restrict__ wf,   // MODE0: e0f[3][16]; else packed [3][16][16]
    const float* __restrict__ cb,
    const float* __restrict__ wg,
    const float* __restrict__ gb,
    const float* __restrict__ rw,   // packed [i][o], MODE 0/1
    const float* __restrict__ rb,
    const float* __restrict__ mx,   // mixer row slice for this layer [16]
    float* __restrict__ skip,
    float* __restrict__ out,
    int d)
{
    const int j = blockIdx.x * 256 + threadIdx.x;   // j in [0, HALF)
    const int t = j & (TL - 1);

    float f0[16], q0[16], f1[16], q1[16];
    #pragma unroll
    for (int o = 0; o < 16; ++o) {
        f0[o] = cb[o];  f1[o] = f0[o];
        q0[o] = gb[o];  q1[o] = q0[o];
    }

    float hcA[16], hcB[16];   // h at tap t (kept for residual)

    if (MODE == 0) {
        float xA2 = x[j];
        float xA1 = (t >= 1) ? x[j - 1] : 0.f;
        float xA0 = (t >= 2) ? x[j - 2] : 0.f;
        float xB2 = x[j + HALF];
        float xB1 = (t >= 1) ? x[j + HALF - 1] : 0.f;
        float xB0 = (t >= 2) ? x[j + HALF - 2] : 0.f;
        float xsA[3] = {xA0, xA1, xA2};
        float xsB[3] = {xB0, xB1, xB2};
        #pragma unroll
        for (int k = 0; k < 3; ++k) {
            const float va = xsA[k], vb = xsB[k];
            #pragma unroll
            for (int o = 0; o < 16; ++o) {
                f0[o] += wf[k * 16 + o] * va;
                f1[o] += wf[k * 16 + o] * vb;
                q0[o] += wg[k * 16 + o] * va;
                q1[o] += wg[k * 16 + o] * vb;
            }
        }
        #pragma unroll
        for (int o = 0; o < 16; ++o) {
            hcA[o] = start_w[o] * xA2;
            hcB[o] = start_w[o] * xB2;
        }
    } else {
        // tap-by-tap: one tap pair (32 floats) live at a time; compiler has
        // ~120 spare VGPRs to hoist/pipeline loads as it sees fit.
        #pragma unroll
        for (int k = 0; k < 3; ++k) {
            const int off = (k - 2) * d;
            const bool ok = (t + off) >= 0;
            const float4* pA = (const float4*)(h_in + (size_t)(j + off) * 16);
            const float4* pB = (const float4*)(h_in + ((size_t)(j + HALF + off)) * 16);
            float inA[16], inB[16];
            #pragma unroll
            for (int q = 0; q < 4; ++q) {
                float4 a = ok ? pA[q] : make_float4(0.f, 0.f, 0.f, 0.f);
                float4 b = ok ? pB[q] : make_float4(0.f, 0.f, 0.f, 0.f);
                inA[q * 4 + 0] = a.x; inA[q * 4 + 1] = a.y;
                inA[q * 4 + 2] = a.z; inA[q * 4 + 3] = a.w;
                inB[q * 4 + 0] = b.x; inB[q * 4 + 1] = b.y;
                inB[q * 4 + 2] = b.z; inB[q * 4 + 3] = b.w;
            }
            #pragma unroll
            for (int i = 0; i < 16; ++i) {
                const float va = inA[i], vb = inB[i];
                const float* __restrict__ pw = wf + (k * 16 + i) * 16;
                const float* __restrict__ pg = wg + (k * 16 + i) * 16;
                #pragma unroll
                for (int o = 0; o < 16; ++o) {
                    f0[o] += pw[o] * va;
                    f1[o] += pw[o] * vb;
                    q0[o] += pg[o] * va;
                    q1[o] += pg[o] * vb;
                }
            }
            if (k == 2) {
                #pragma unroll
                for (int i = 0; i < 16; ++i) { hcA[i] = inA[i]; hcB[i] = inB[i]; }
            }
        }
    }

    float zA[16], zB[16];
    #pragma unroll
    for (int o = 0; o < 16; ++o) {
        zA[o] = softsign_f(f0[o]) * softsign_f(q0[o]);
        zB[o] = softsign_f(f1[o]) * softsign_f(q1[o]);
    }

    float sA = 0.f, sB = 0.f;
    #pragma unroll
    for (int o = 0; o < 16; ++o) {
        sA += mx[o] * zA[o];
        sB += mx[o] * zB[o];
    }

    if (MODE == 0) {
        skip[j] = sA;  skip[j + HALF] = sB;
    } else if (MODE == 1) {
        skip[j] += sA; skip[j + HALF] += sB;
    } else {
        out[j] = skip[j] + sA;
        out[j + HALF] = skip[j + HALF] + sB;
    }

    if (MODE != 2) {
        float hnA[16], hnB[16];
        #pragma unroll
        for (int o = 0; o < 16; ++o) {
            hnA[o] = hcA[o] + rb[o];
            hnB[o] = hcB[o] + rb[o];
        }
        #pragma unroll
        for (int i = 0; i < 16; ++i) {
            const float va = zA[i], vb = zB[i];
            const float* __restrict__ pr = rw + i * 16;
            #pragma unroll
            for (int o = 0; o < 16; ++o) {
                hnA[o] += pr[o] * va;
                hnB[o] += pr[o] * vb;
            }
        }
        float4* qA = (float4*)(h_out + (size_t)j * 16);
        float4* qB = (float4*)(h_out + ((size_t)j + HALF) * 16);
        qA[0] = make_float4(hnA[0],  hnA[1],  hnA[2],  hnA[3]);
        qA[1] = make_float4(hnA[4],  hnA[5],  hnA[6],  hnA[7]);
        qA[2] = make_float4(hnA[8],  hnA[9],  hnA[10], hnA[11]);
        qA[3] = make_float4(hnA[12], hnA[13], hnA[14], hnA[15]);
        qB[0] = make_float4(hnB[0],  hnB[1],  hnB[2],  hnB[3]);
        qB[1] = make_float4(hnB[4],  hnB[5],  hnB[6],  hnB[7]);
        qB[2] = make_float4(hnB[8],  hnB[9],  hnB[10], hnB[11]);
        qB[3] = make_float4(hnB[12], hnB[13], hnB[14], hnB[15]);
    }
}

extern "C" void kernel_launch(void* const* d_in, const int* in_sizes, int n_in,
                              void* d_out, int out_size, void* d_ws, size_t ws_size,
                              hipStream_t stream) {
    const float* x       = (const float*)d_in[0];
    const float* start_w = (const float*)d_in[1];
    const float* conv_w  = (const float*)d_in[2];
    const float* conv_b  = (const float*)d_in[3];
    const float* gate_w  = (const float*)d_in[4];
    const float* gate_b  = (const float*)d_in[5];
    const float* res_w   = (const float*)d_in[6];
    const float* res_b   = (const float*)d_in[7];
    const float* mixer_w = (const float*)d_in[8];
    float* out = (float*)d_out;

    // ws layout (floats):
    float* ws  = (float*)d_ws;
    float* wf  = ws;                 // 13824  packed conv weights
    float* wg  = wf + 13824;         // 13824  packed gate weights
    float* rw  = wg + 13824;         // 4352   packed res weights
    float* e0f = rw + 4352;          // 48     layer0 folded conv weights
    float* e0g = e0f + 48;           // 48
    float* hA  = e0g + 48;           // 4194304  h ping
    float* hB  = hA + 4194304;       // 4194304  h pong
    float* skip = hB + 4194304;      // 262144   running mixer accumulation
    (void)ws_size; (void)in_sizes; (void)n_in; (void)out_size;

    pack_kernel<<<72, 256, 0, stream>>>(start_w, conv_w, gate_w, res_w,
                                        wf, wg, rw, e0f, e0g);

    static const int dil[18] = {1,2,4,8,16,32,64,128,256,1,2,4,8,16,32,64,128,256};
    const int nblk = HALF / 256;   // 512 blocks, 2 per CU

    // layer 0 (fused start conv)
    layer_kernel<0><<<nblk, 256, 0, stream>>>(
        x, start_w, nullptr, hA,
        e0f, conv_b, e0g, gate_b,
        rw, res_b, mixer_w, skip, nullptr, 1);

    float* bufs[2] = {hA, hB};
    for (int li = 1; li < 17; ++li) {
        layer_kernel<1><<<nblk, 256, 0, stream>>>(
            nullptr, nullptr, bufs[(li - 1) & 1], bufs[li & 1],
            wf + li * 768, conv_b + li * 16, wg + li * 768, gate_b + li * 16,
            rw + li * 256, res_b + li * 16, mixer_w + li * 16,
            skip, nullptr, dil[li]);
    }

    // layer 17: no residual, writes final out = skip + contribution
    layer_kernel<2><<<nblk, 256, 0, stream>>>(
        nullptr, nullptr, bufs[0], nullptr,
        wf + 17 * 768, conv_b + 17 * 16, wg + 17 * 768, gate_b + 17 * 16,
        nullptr, nullptr, mixer_w + 17 * 16,
        skip, out, dil[17]);
}

// Round 6
// 582.173 us; speedup vs baseline: 7.4244x; 7.2888x over previous
//
#include <hip/hip_runtime.h>
#include <math.h>

// WaveNet on MI355X — round 6.
// R3/R4/R5 all hit the same allocator pathology: live set >~128 floats ->
// compiler picks ~96 VGPRs regardless of launch_bounds/waves_per_eu and
// emits spill + remat storms (WRITE excess 18MB, VALU 25x useful work).
// Fix by code shape, not attributes: TPT=1, tap-by-tap (one 16-float tap
// live), NO hc carry (reload tap k=2 from L1 for the residual), k-loop not
// unrolled (3 small scheduling regions). Live set ~65 floats -> fits any
// plausible allocation. Weights via uniform global loads (s_load proven).

constexpr int TL = 65536;    // T
constexpr int NTOT = 262144; // B*T

// ---------------- weight packing ----------------
// conv_w/gate_w [18][o=16][i=16][k=3] -> packed [18][k=3][i=16][o=16]  (o fastest)
// res_w [17][o=16][i=16] -> [17][i=16][o=16]
// layer-0 folded with start_w: e0f[k][o] = sum_i conv_w[0][o][i][k]*start_w[i]
__global__ __launch_bounds__(256) void pack_kernel(
    const float* __restrict__ start_w,
    const float* __restrict__ conv_w,
    const float* __restrict__ gate_w,
    const float* __restrict__ res_w,
    float* __restrict__ wf, float* __restrict__ wg,
    float* __restrict__ rw, float* __restrict__ e0f, float* __restrict__ e0g)
{
    int idx = blockIdx.x * 256 + threadIdx.x;
    if (idx < 13824) {
        int li = idx / 768;
        int r  = idx % 768;
        int k  = r / 256;
        int i  = (r / 16) % 16;
        int o  = r % 16;
        int src = ((li * 16 + o) * 16 + i) * 3 + k;
        wf[idx] = conv_w[src];
        wg[idx] = gate_w[src];
    } else if (idx < 13824 + 4352) {
        int j  = idx - 13824;
        int li = j / 256;
        int r  = j % 256;
        int i  = r / 16;
        int o  = r % 16;
        rw[j] = res_w[(li * 16 + o) * 16 + i];
    } else if (idx < 13824 + 4352 + 96) {
        int j = idx - 13824 - 4352;   // [0,96): 48 for f, 48 for g
        int which = j / 48;
        int r = j % 48;
        int k = r / 16;
        int o = r % 16;
        const float* src = which ? gate_w : conv_w;
        float s = 0.f;
        #pragma unroll
        for (int i = 0; i < 16; ++i) s += src[(o * 16 + i) * 3 + k] * start_w[i];
        (which ? e0g : e0f)[k * 16 + o] = s;
    }
}

__device__ __forceinline__ float softsign_f(float v) {
    return v * __builtin_amdgcn_rcpf(1.0f + fabsf(v));
}

// ---------------- fused layer kernel ----------------
// MODE 0: first layer (x via folded start conv; writes h_out, skip=)
// MODE 1: middle layer (reads h_in, writes h_out, skip+=)
// MODE 2: last layer (reads h_in, no residual, out = skip + contribution)
template <int MODE>
__global__ __launch_bounds__(256, 4) void layer_kernel(
    const float* __restrict__ x,
    const float* __restrict__ start_w,
    const float* __restrict__ h_in,
    float* __restrict__ h_out,
    const float* __restrict__ wf,   // MODE0: e0f[3][16]; else packed [3][16][16]
    const float* __restrict__ cb,
    const float* __restrict__ wg,
    const float* __restrict__ gb,
    const float* __restrict__ rw,   // packed [i][o], MODE 0/1
    const float* __restrict__ rb,
    const float* __restrict__ mx,   // mixer row slice for this layer [16]
    float* __restrict__ skip,
    float* __restrict__ out,
    int d)
{
    const int j = blockIdx.x * 256 + threadIdx.x;   // j in [0, NTOT)
    const int t = j & (TL - 1);

    float f[16], q[16];
    #pragma unroll
    for (int o = 0; o < 16; ++o) { f[o] = cb[o]; q[o] = gb[o]; }

    if (MODE == 0) {
        float x2 = x[j];
        float x1 = (t >= 1) ? x[j - 1] : 0.f;
        float x0 = (t >= 2) ? x[j - 2] : 0.f;
        float xs[3] = {x0, x1, x2};
        #pragma unroll
        for (int k = 0; k < 3; ++k) {
            const float v = xs[k];
            #pragma unroll
            for (int o = 0; o < 16; ++o) {
                f[o] += wf[k * 16 + o] * v;
                q[o] += wg[k * 16 + o] * v;
            }
        }
    } else {
        // tap-by-tap, k loop NOT unrolled: three small scheduling regions,
        // live set per region = 32 accumulators + 16 tap floats + temps.
        #pragma unroll 1
        for (int k = 0; k < 3; ++k) {
            const int off = (k - 2) * d;
            const bool ok = (t + off) >= 0;
            const float4* p = (const float4*)(h_in + (size_t)(j + off) * 16);
            float in[16];
            #pragma unroll
            for (int u = 0; u < 4; ++u) {
                float4 a = ok ? p[u] : make_float4(0.f, 0.f, 0.f, 0.f);
                in[u * 4 + 0] = a.x; in[u * 4 + 1] = a.y;
                in[u * 4 + 2] = a.z; in[u * 4 + 3] = a.w;
            }
            const float* __restrict__ pw = wf + k * 256;
            const float* __restrict__ pg = wg + k * 256;
            #pragma unroll
            for (int i = 0; i < 16; ++i) {
                const float v = in[i];
                #pragma unroll
                for (int o = 0; o < 16; ++o) {
                    f[o] += pw[i * 16 + o] * v;
                    q[o] += pg[i * 16 + o] * v;
                }
            }
        }
    }

    float z[16];
    #pragma unroll
    for (int o = 0; o < 16; ++o) z[o] = softsign_f(f[o]) * softsign_f(q[o]);

    float s = 0.f;
    #pragma unroll
    for (int o = 0; o < 16; ++o) s += mx[o] * z[o];

    if (MODE == 0) {
        skip[j] = s;
    } else if (MODE == 1) {
        skip[j] += s;
    } else {
        out[j] = skip[j] + s;
        return;
    }

    // residual: reload h(t) (tap k=2) — L1-hot 64B — instead of carrying it
    // in registers through the conv.
    float hn[16];
    if (MODE == 0) {
        float x2 = x[j];
        #pragma unroll
        for (int o = 0; o < 16; ++o) hn[o] = start_w[o] * x2 + rb[o];
    } else {
        const float4* p2 = (const float4*)(h_in + (size_t)j * 16);
        #pragma unroll
        for (int u = 0; u < 4; ++u) {
            float4 a = p2[u];
            hn[u * 4 + 0] = a.x + rb[u * 4 + 0];
            hn[u * 4 + 1] = a.y + rb[u * 4 + 1];
            hn[u * 4 + 2] = a.z + rb[u * 4 + 2];
            hn[u * 4 + 3] = a.w + rb[u * 4 + 3];
        }
    }
    #pragma unroll
    for (int i = 0; i < 16; ++i) {
        const float v = z[i];
        const float* __restrict__ pr = rw + i * 16;
        #pragma unroll
        for (int o = 0; o < 16; ++o) hn[o] += pr[o] * v;
    }
    float4* qo = (float4*)(h_out + (size_t)j * 16);
    qo[0] = make_float4(hn[0],  hn[1],  hn[2],  hn[3]);
    qo[1] = make_float4(hn[4],  hn[5],  hn[6],  hn[7]);
    qo[2] = make_float4(hn[8],  hn[9],  hn[10], hn[11]);
    qo[3] = make_float4(hn[12], hn[13], hn[14], hn[15]);
}

extern "C" void kernel_launch(void* const* d_in, const int* in_sizes, int n_in,
                              void* d_out, int out_size, void* d_ws, size_t ws_size,
                              hipStream_t stream) {
    const float* x       = (const float*)d_in[0];
    const float* start_w = (const float*)d_in[1];
    const float* conv_w  = (const float*)d_in[2];
    const float* conv_b  = (const float*)d_in[3];
    const float* gate_w  = (const float*)d_in[4];
    const float* gate_b  = (const float*)d_in[5];
    const float* res_w   = (const float*)d_in[6];
    const float* res_b   = (const float*)d_in[7];
    const float* mixer_w = (const float*)d_in[8];
    float* out = (float*)d_out;

    // ws layout (floats):
    float* ws  = (float*)d_ws;
    float* wf  = ws;                 // 13824  packed conv weights
    float* wg  = wf + 13824;         // 13824  packed gate weights
    float* rw  = wg + 13824;         // 4352   packed res weights
    float* e0f = rw + 4352;          // 48     layer0 folded conv weights
    float* e0g = e0f + 48;           // 48
    float* hA  = e0g + 48;           // 4194304  h ping
    float* hB  = hA + 4194304;       // 4194304  h pong
    float* skip = hB + 4194304;      // 262144   running mixer accumulation
    (void)ws_size; (void)in_sizes; (void)n_in; (void)out_size;

    pack_kernel<<<72, 256, 0, stream>>>(start_w, conv_w, gate_w, res_w,
                                        wf, wg, rw, e0f, e0g);

    static const int dil[18] = {1,2,4,8,16,32,64,128,256,1,2,4,8,16,32,64,128,256};
    const int nblk = NTOT / 256;   // 1024 blocks, 4 per CU

    // layer 0 (fused start conv)
    layer_kernel<0><<<nblk, 256, 0, stream>>>(
        x, start_w, nullptr, hA,
        e0f, conv_b, e0g, gate_b,
        rw, res_b, mixer_w, skip, nullptr, 1);

    float* bufs[2] = {hA, hB};
    for (int li = 1; li < 17; ++li) {
        layer_kernel<1><<<nblk, 256, 0, stream>>>(
            nullptr, nullptr, bufs[(li - 1) & 1], bufs[li & 1],
            wf + li * 768, conv_b + li * 16, wg + li * 768, gate_b + li * 16,
            rw + li * 256, res_b + li * 16, mixer_w + li * 16,
            skip, nullptr, dil[li]);
    }

    // layer 17: no residual, writes final out = skip + contribution
    layer_kernel<2><<<nblk, 256, 0, stream>>>(
        nullptr, nullptr, bufs[0], nullptr,
        wf + 17 * 768, conv_b + 17 * 16, wg + 17 * 768, gate_b + 17 * 16,
        nullptr, nullptr, mixer_w + 17 * 16,
        skip, out, dil[17]);
}

// Round 7
// 399.360 us; speedup vs baseline: 10.8230x; 1.4578x over previous
//
#include <hip/hip_runtime.h>
#include <hip/hip_bf16.h>
#include <math.h>

// WaveNet on MI355X — round 7: MFMA rewrite.
// R2/R6 both plateau at ~30us/layer: scalar-FMA path is s_load/latency bound
// (1536 FMAs/thread fed from K$ with ~6-deep s_load windows). Move the conv
// to matrix cores: per wave one 32x32 tile, A=[32 rows x K16/tap] taps of h,
// B=[16 x 32] weights (f|g), 3 taps x 4 split-bf16 products = 12 MFMAs.
// h stored as two bf16 planes (hi,lo) -> A-frags are raw short8 loads.
// Epilogue: LDS 32x36 transpose, softsign/z fp32, mixer via shfl_xor(32),
// residual fp32 VALU (rw via L1-hot float4), h re-split to planes.

typedef __attribute__((ext_vector_type(8))) short short8;
typedef __attribute__((ext_vector_type(16))) float f32x16;

constexpr int TL = 65536;    // T
constexpr int NTOT = 262144; // B*T

__device__ __forceinline__ unsigned short f2bf(float v) {
    __hip_bfloat16 b = __float2bfloat16(v);
    unsigned short u; __builtin_memcpy(&u, &b, 2); return u;
}
__device__ __forceinline__ float bf2f(unsigned short u) {
    unsigned int x = ((unsigned int)u) << 16;
    float f; __builtin_memcpy(&f, &x, 4); return f;
}
__device__ __forceinline__ float softsign_f(float v) {
    return v * __builtin_amdgcn_rcpf(1.0f + fabsf(v));
}

// ---------------- weight packing ----------------
// bfrag[li][tap][plane][lane][j]: B-fragment for mfma_f32_32x32x16_bf16.
//   lane: col n = lane&31 (n<16 -> f output o=n, else g output o=n-16),
//         k-half = lane>>5;  elem j: k = (lane>>5)*8 + j = input channel.
//   plane 0 = bf16(w) hi, plane 1 = bf16(w - hi) lo.
// fgbias[li][32]: conv_b | gate_b by col.  rwp[li][i][o] = res_w[li][o][i].
// e0f/e0g[k][o]: layer-0 conv folded with start_w.
__global__ __launch_bounds__(256) void pack_kernel(
    const float* __restrict__ start_w,
    const float* __restrict__ conv_w,
    const float* __restrict__ gate_w,
    const float* __restrict__ res_w,
    const float* __restrict__ conv_b,
    const float* __restrict__ gate_b,
    unsigned short* __restrict__ bfrag,
    float* __restrict__ fgbias,
    float* __restrict__ rwp,
    float* __restrict__ e0f, float* __restrict__ e0g)
{
    int idx = blockIdx.x * 256 + threadIdx.x;
    if (idx < 55296) {                       // 18*3*2*64*8
        int li = idx / 3072, r = idx % 3072;
        int tap = r / 1024, r2 = r % 1024;
        int p = r2 / 512, r3 = r2 % 512;
        int lane = r3 / 8, j = r3 % 8;
        int n = lane & 31, kh = lane >> 5;
        int i_ch = kh * 8 + j, o = n & 15;
        const float* src = (n < 16) ? conv_w : gate_w;
        float w = src[((li * 16 + o) * 16 + i_ch) * 3 + tap];
        unsigned short hi = f2bf(w);
        bfrag[idx] = (p == 0) ? hi : f2bf(w - bf2f(hi));
    } else if (idx < 55296 + 576) {
        int u = idx - 55296; int li = u / 32, n = u % 32;
        fgbias[u] = (n < 16) ? conv_b[li * 16 + n] : gate_b[li * 16 + n - 16];
    } else if (idx < 55296 + 576 + 4352) {
        int u = idx - 55872; int li = u / 256, r = u % 256, i = r / 16, o = r % 16;
        rwp[u] = res_w[(li * 16 + o) * 16 + i];
    } else if (idx < 60320) {
        int u = idx - 60224; int which = u / 48, r = u % 48, k = r / 16, o = r % 16;
        const float* src = which ? gate_w : conv_w;
        float s = 0.f;
        #pragma unroll
        for (int i = 0; i < 16; ++i) s += src[(o * 16 + i) * 3 + k] * start_w[i];
        (which ? e0g : e0f)[k * 16 + o] = s;
    }
}

// ---------------- layer 0 (VALU; tiny: 96 conv FMAs) ----------------
__global__ __launch_bounds__(256) void layer0_kernel(
    const float* __restrict__ x, const float* __restrict__ start_w,
    const float* __restrict__ e0f, const float* __restrict__ cb,
    const float* __restrict__ e0g, const float* __restrict__ gb,
    const float* __restrict__ rwp, const float* __restrict__ rb,
    const float* __restrict__ mx,
    unsigned short* __restrict__ hHi, unsigned short* __restrict__ hLo,
    float* __restrict__ skip)
{
    const int j = blockIdx.x * 256 + threadIdx.x;
    const int t = j & (TL - 1);
    float x2 = x[j];
    float x1 = (t >= 1) ? x[j - 1] : 0.f;
    float x0 = (t >= 2) ? x[j - 2] : 0.f;
    float xs[3] = {x0, x1, x2};
    float f[16], q[16];
    #pragma unroll
    for (int o = 0; o < 16; ++o) { f[o] = cb[o]; q[o] = gb[o]; }
    #pragma unroll
    for (int k = 0; k < 3; ++k) {
        const float v = xs[k];
        #pragma unroll
        for (int o = 0; o < 16; ++o) {
            f[o] += e0f[k * 16 + o] * v;
            q[o] += e0g[k * 16 + o] * v;
        }
    }
    float z[16];
    #pragma unroll
    for (int o = 0; o < 16; ++o) z[o] = softsign_f(f[o]) * softsign_f(q[o]);
    float s = 0.f;
    #pragma unroll
    for (int o = 0; o < 16; ++o) s += mx[o] * z[o];
    skip[j] = s;
    float hn[16];
    #pragma unroll
    for (int o = 0; o < 16; ++o) hn[o] = start_w[o] * x2 + rb[o];
    #pragma unroll
    for (int i = 0; i < 16; ++i) {
        const float v = z[i];
        #pragma unroll
        for (int o = 0; o < 16; ++o) hn[o] += rwp[i * 16 + o] * v;
    }
    short8 hi8[2], lo8[2];
    #pragma unroll
    for (int o = 0; o < 16; ++o) {
        unsigned short h = f2bf(hn[o]);
        hi8[o >> 3][o & 7] = (short)h;
        lo8[o >> 3][o & 7] = (short)f2bf(hn[o] - bf2f(h));
    }
    *(short8*)(hHi + (size_t)j * 16)     = hi8[0];
    *(short8*)(hHi + (size_t)j * 16 + 8) = hi8[1];
    *(short8*)(hLo + (size_t)j * 16)     = lo8[0];
    *(short8*)(hLo + (size_t)j * 16 + 8) = lo8[1];
}

// ---------------- MFMA layer kernel ----------------
// MODE 1: middle layer (skip+=, writes h planes). MODE 2: last (out=skip+s).
template <int MODE>
__global__ __launch_bounds__(256) void layer_mfma(
    const unsigned short* __restrict__ hHi_in,
    const unsigned short* __restrict__ hLo_in,
    unsigned short* __restrict__ hHi_out,
    unsigned short* __restrict__ hLo_out,
    const unsigned short* __restrict__ bfrag_l,  // 3072 ushorts
    const float* __restrict__ fgbias_l,          // 32
    const float* __restrict__ rwp_l,             // 256 (MODE 1)
    const float* __restrict__ rb_l,              // 16  (MODE 1)
    const float* __restrict__ mx_l,              // 16
    float* __restrict__ skip,
    float* __restrict__ out,
    int d)
{
    __shared__ float lds[4 * 32 * 36];
    const int wid  = threadIdx.x >> 6;
    const int lane = threadIdx.x & 63;
    const int r0 = lane & 31;          // tile row (t) AND C col via lane&31
    const int kh = lane >> 5;          // k-half / o-half
    const int j  = blockIdx.x * 128 + wid * 32 + r0;
    const int t  = j & (TL - 1);

    short8 zero8;
    #pragma unroll
    for (int e = 0; e < 8; ++e) zero8[e] = 0;

    // ---- A fragments: 3 taps x (hi,lo), lane holds row r0, ch kh*8..+8 ----
    short8 ahi[3], alo[3];
    #pragma unroll
    for (int k = 0; k < 3; ++k) {
        const int off = (k - 2) * d;
        const bool ok = (t + off) >= 0;
        const size_t base = (size_t)(ok ? (j + off) : j) * 16 + kh * 8;
        short8 h = *(const short8*)(hHi_in + base);
        short8 l = *(const short8*)(hLo_in + base);
        if (!ok) { h = zero8; l = zero8; }
        ahi[k] = h; alo[k] = l;
    }

    // ---- conv+gate: acc[col n] init = bias, 12 MFMAs ----
    const float bias = fgbias_l[r0];
    f32x16 acc;
    #pragma unroll
    for (int i = 0; i < 16; ++i) acc[i] = bias;
    const short8* bf = (const short8*)bfrag_l;   // [(tap*2+p)*64 + lane]
    #pragma unroll
    for (int k = 0; k < 3; ++k) {
        short8 bhi = bf[(k * 2 + 0) * 64 + lane];
        short8 blo = bf[(k * 2 + 1) * 64 + lane];
        acc = __builtin_amdgcn_mfma_f32_32x32x16_bf16(ahi[k], bhi, acc, 0, 0, 0);
        acc = __builtin_amdgcn_mfma_f32_32x32x16_bf16(ahi[k], blo, acc, 0, 0, 0);
        acc = __builtin_amdgcn_mfma_f32_32x32x16_bf16(alo[k], bhi, acc, 0, 0, 0);
        acc = __builtin_amdgcn_mfma_f32_32x32x16_bf16(alo[k], blo, acc, 0, 0, 0);
    }

    // ---- transpose C (col=lane&31, row=(r&3)+8*(r>>2)+4*kh) via LDS ----
    const int wbase = wid * 32 * 36;
    #pragma unroll
    for (int r = 0; r < 16; ++r) {
        const int row = (r & 3) + 8 * (r >> 2) + 4 * kh;
        lds[wbase + row * 36 + r0] = acc[r];
    }
    const int rbase = wbase + r0 * 36 + kh * 8;
    float4 f0v = *(float4*)&lds[rbase];
    float4 f1v = *(float4*)&lds[rbase + 4];
    float4 g0v = *(float4*)&lds[rbase + 16];
    float4 g1v = *(float4*)&lds[rbase + 20];

    float z8[8];
    z8[0] = softsign_f(f0v.x) * softsign_f(g0v.x);
    z8[1] = softsign_f(f0v.y) * softsign_f(g0v.y);
    z8[2] = softsign_f(f0v.z) * softsign_f(g0v.z);
    z8[3] = softsign_f(f0v.w) * softsign_f(g0v.w);
    z8[4] = softsign_f(f1v.x) * softsign_f(g1v.x);
    z8[5] = softsign_f(f1v.y) * softsign_f(g1v.y);
    z8[6] = softsign_f(f1v.z) * softsign_f(g1v.z);
    z8[7] = softsign_f(f1v.w) * softsign_f(g1v.w);

    // ---- mixer dot (per row, halves combined via shfl_xor 32) ----
    float4 m0 = *(const float4*)(mx_l + kh * 8);
    float4 m1 = *(const float4*)(mx_l + kh * 8 + 4);
    float part = m0.x*z8[0] + m0.y*z8[1] + m0.z*z8[2] + m0.w*z8[3]
               + m1.x*z8[4] + m1.y*z8[5] + m1.z*z8[6] + m1.w*z8[7];
    float tot = part + __shfl_xor(part, 32);

    if (MODE == 2) {
        if (kh == 0) out[j] = skip[j] + tot;
        return;
    }
    if (kh == 0) skip[j] += tot;

    // ---- full z row (other half via shfl_xor 32) ----
    float zf[16];
    #pragma unroll
    for (int jo = 0; jo < 8; ++jo) {
        zf[kh * 8 + jo]       = z8[jo];
        zf[(1 - kh) * 8 + jo] = __shfl_xor(z8[jo], 32);
    }

    // ---- residual: hn = h(t) + rb + z @ rw  (fp32 VALU) ----
    float hn[8];
    float4 rb0 = *(const float4*)(rb_l + kh * 8);
    float4 rb1 = *(const float4*)(rb_l + kh * 8 + 4);
    hn[0] = bf2f((unsigned short)ahi[2][0]) + bf2f((unsigned short)alo[2][0]) + rb0.x;
    hn[1] = bf2f((unsigned short)ahi[2][1]) + bf2f((unsigned short)alo[2][1]) + rb0.y;
    hn[2] = bf2f((unsigned short)ahi[2][2]) + bf2f((unsigned short)alo[2][2]) + rb0.z;
    hn[3] = bf2f((unsigned short)ahi[2][3]) + bf2f((unsigned short)alo[2][3]) + rb0.w;
    hn[4] = bf2f((unsigned short)ahi[2][4]) + bf2f((unsigned short)alo[2][4]) + rb1.x;
    hn[5] = bf2f((unsigned short)ahi[2][5]) + bf2f((unsigned short)alo[2][5]) + rb1.y;
    hn[6] = bf2f((unsigned short)ahi[2][6]) + bf2f((unsigned short)alo[2][6]) + rb1.z;
    hn[7] = bf2f((unsigned short)ahi[2][7]) + bf2f((unsigned short)alo[2][7]) + rb1.w;
    #pragma unroll 4
    for (int i = 0; i < 16; ++i) {
        const float zi = zf[i];
        float4 wA = *(const float4*)(rwp_l + i * 16 + kh * 8);
        float4 wB = *(const float4*)(rwp_l + i * 16 + kh * 8 + 4);
        hn[0] += wA.x * zi; hn[1] += wA.y * zi;
        hn[2] += wA.z * zi; hn[3] += wA.w * zi;
        hn[4] += wB.x * zi; hn[5] += wB.y * zi;
        hn[6] += wB.z * zi; hn[7] += wB.w * zi;
    }

    // ---- store h as split bf16 planes ----
    short8 hi8, lo8;
    #pragma unroll
    for (int jo = 0; jo < 8; ++jo) {
        unsigned short h = f2bf(hn[jo]);
        hi8[jo] = (short)h;
        lo8[jo] = (short)f2bf(hn[jo] - bf2f(h));
    }
    *(short8*)(hHi_out + (size_t)j * 16 + kh * 8) = hi8;
    *(short8*)(hLo_out + (size_t)j * 16 + kh * 8) = lo8;
}

extern "C" void kernel_launch(void* const* d_in, const int* in_sizes, int n_in,
                              void* d_out, int out_size, void* d_ws, size_t ws_size,
                              hipStream_t stream) {
    const float* x       = (const float*)d_in[0];
    const float* start_w = (const float*)d_in[1];
    const float* conv_w  = (const float*)d_in[2];
    const float* conv_b  = (const float*)d_in[3];
    const float* gate_w  = (const float*)d_in[4];
    const float* gate_b  = (const float*)d_in[5];
    const float* res_w   = (const float*)d_in[6];
    const float* res_b   = (const float*)d_in[7];
    const float* mixer_w = (const float*)d_in[8];
    float* out = (float*)d_out;

    float* ws = (float*)d_ws;
    unsigned short* bfrag = (unsigned short*)ws;            // 55296 ushorts
    float* fgbias = ws + 27648;                             // 576
    float* rwp    = fgbias + 576;                           // 4352
    float* e0f    = rwp + 4352;                             // 48
    float* e0g    = e0f + 48;                               // 48
    unsigned short* hHiA = (unsigned short*)(e0g + 48);     // 4 planes x 8MB
    unsigned short* hLoA = hHiA + 4194304;
    unsigned short* hHiB = hLoA + 4194304;
    unsigned short* hLoB = hHiB + 4194304;
    float* skip = (float*)(hLoB + 4194304);                 // 262144
    (void)ws_size; (void)in_sizes; (void)n_in; (void)out_size;

    pack_kernel<<<236, 256, 0, stream>>>(start_w, conv_w, gate_w, res_w,
                                         conv_b, gate_b,
                                         bfrag, fgbias, rwp, e0f, e0g);

    static const int dil[18] = {1,2,4,8,16,32,64,128,256,1,2,4,8,16,32,64,128,256};

    // layer 0 (VALU, writes plane set A + skip)
    layer0_kernel<<<NTOT / 256, 256, 0, stream>>>(
        x, start_w, e0f, conv_b, e0g, gate_b,
        rwp, res_b, mixer_w, hHiA, hLoA, skip);

    unsigned short* hi[2] = {hHiA, hHiB};
    unsigned short* lo[2] = {hLoA, hLoB};
    const int nblk = NTOT / 128;   // 2048 blocks, 128 rows each

    for (int li = 1; li < 17; ++li) {
        const int pin = (li - 1) & 1, pout = li & 1;
        layer_mfma<1><<<nblk, 256, 0, stream>>>(
            hi[pin], lo[pin], hi[pout], lo[pout],
            bfrag + li * 3072, fgbias + li * 32,
            rwp + li * 256, res_b + li * 16, mixer_w + li * 16,
            skip, nullptr, dil[li]);
    }

    // layer 17: out = skip + contribution
    layer_mfma<2><<<nblk, 256, 0, stream>>>(
        hi[0], lo[0], nullptr, nullptr,
        bfrag + 17 * 3072, fgbias + 17 * 32,
        nullptr, nullptr, mixer_w + 17 * 16,
        skip, out, dil[17]);
}

// Round 8
// 342.318 us; speedup vs baseline: 12.6265x; 1.1666x over previous
//
#include <hip/hip_runtime.h>
#include <hip/hip_bf16.h>
#include <math.h>

// WaveNet on MI355X — round 8.
// R7 (MFMA rewrite) landed at ~20.6us/layer: HBM-bound with broken XCD
// locality — tap look-backs (<=16KB) land in OTHER XCDs' L2 under default
// round-robin dispatch. Fixes:
//  1) XCD-chunked block swizzle: XCD x owns a contiguous time chunk, same
//     binding every layer -> taps + cross-layer h reuse become L2-local.
//  2) rwp/rb/mx staged in LDS -> kills 32 per-lane VMEM loads in epilogue.
//  3) drop lo*lo MFMA product (9 MFMAs/tile, ~1e-4 contribution).

typedef __attribute__((ext_vector_type(8))) short short8;
typedef __attribute__((ext_vector_type(16))) float f32x16;

constexpr int TL = 65536;    // T
constexpr int NTOT = 262144; // B*T

__device__ __forceinline__ unsigned short f2bf(float v) {
    __hip_bfloat16 b = __float2bfloat16(v);
    unsigned short u; __builtin_memcpy(&u, &b, 2); return u;
}
__device__ __forceinline__ float bf2f(unsigned short u) {
    unsigned int x = ((unsigned int)u) << 16;
    float f; __builtin_memcpy(&f, &x, 4); return f;
}
__device__ __forceinline__ float softsign_f(float v) {
    return v * __builtin_amdgcn_rcpf(1.0f + fabsf(v));
}

// ---------------- weight packing (unchanged from R7) ----------------
__global__ __launch_bounds__(256) void pack_kernel(
    const float* __restrict__ start_w,
    const float* __restrict__ conv_w,
    const float* __restrict__ gate_w,
    const float* __restrict__ res_w,
    const float* __restrict__ conv_b,
    const float* __restrict__ gate_b,
    unsigned short* __restrict__ bfrag,
    float* __restrict__ fgbias,
    float* __restrict__ rwp,
    float* __restrict__ e0f, float* __restrict__ e0g)
{
    int idx = blockIdx.x * 256 + threadIdx.x;
    if (idx < 55296) {                       // 18*3*2*64*8
        int li = idx / 3072, r = idx % 3072;
        int tap = r / 1024, r2 = r % 1024;
        int p = r2 / 512, r3 = r2 % 512;
        int lane = r3 / 8, j = r3 % 8;
        int n = lane & 31, kh = lane >> 5;
        int i_ch = kh * 8 + j, o = n & 15;
        const float* src = (n < 16) ? conv_w : gate_w;
        float w = src[((li * 16 + o) * 16 + i_ch) * 3 + tap];
        unsigned short hi = f2bf(w);
        bfrag[idx] = (p == 0) ? hi : f2bf(w - bf2f(hi));
    } else if (idx < 55296 + 576) {
        int u = idx - 55296; int li = u / 32, n = u % 32;
        fgbias[u] = (n < 16) ? conv_b[li * 16 + n] : gate_b[li * 16 + n - 16];
    } else if (idx < 55296 + 576 + 4352) {
        int u = idx - 55872; int li = u / 256, r = u % 256, i = r / 16, o = r % 16;
        rwp[u] = res_w[(li * 16 + o) * 16 + i];
    } else if (idx < 60320) {
        int u = idx - 60224; int which = u / 48, r = u % 48, k = r / 16, o = r % 16;
        const float* src = which ? gate_w : conv_w;
        float s = 0.f;
        #pragma unroll
        for (int i = 0; i < 16; ++i) s += src[(o * 16 + i) * 3 + k] * start_w[i];
        (which ? e0g : e0f)[k * 16 + o] = s;
    }
}

// ---------------- layer 0 (VALU; tiny) ----------------
__global__ __launch_bounds__(256) void layer0_kernel(
    const float* __restrict__ x, const float* __restrict__ start_w,
    const float* __restrict__ e0f, const float* __restrict__ cb,
    const float* __restrict__ e0g, const float* __restrict__ gb,
    const float* __restrict__ rwp, const float* __restrict__ rb,
    const float* __restrict__ mx,
    unsigned short* __restrict__ hHi, unsigned short* __restrict__ hLo,
    float* __restrict__ skip)
{
    // same XCD-chunk swizzle as layer_mfma so row->XCD binding is consistent
    const int nb = gridDim.x;
    const int wb = (blockIdx.x & 7) * (nb >> 3) + (blockIdx.x >> 3);
    const int j = wb * 256 + threadIdx.x;
    const int t = j & (TL - 1);
    float x2 = x[j];
    float x1 = (t >= 1) ? x[j - 1] : 0.f;
    float x0 = (t >= 2) ? x[j - 2] : 0.f;
    float xs[3] = {x0, x1, x2};
    float f[16], q[16];
    #pragma unroll
    for (int o = 0; o < 16; ++o) { f[o] = cb[o]; q[o] = gb[o]; }
    #pragma unroll
    for (int k = 0; k < 3; ++k) {
        const float v = xs[k];
        #pragma unroll
        for (int o = 0; o < 16; ++o) {
            f[o] += e0f[k * 16 + o] * v;
            q[o] += e0g[k * 16 + o] * v;
        }
    }
    float z[16];
    #pragma unroll
    for (int o = 0; o < 16; ++o) z[o] = softsign_f(f[o]) * softsign_f(q[o]);
    float s = 0.f;
    #pragma unroll
    for (int o = 0; o < 16; ++o) s += mx[o] * z[o];
    skip[j] = s;
    float hn[16];
    #pragma unroll
    for (int o = 0; o < 16; ++o) hn[o] = start_w[o] * x2 + rb[o];
    #pragma unroll
    for (int i = 0; i < 16; ++i) {
        const float v = z[i];
        #pragma unroll
        for (int o = 0; o < 16; ++o) hn[o] += rwp[i * 16 + o] * v;
    }
    short8 hi8[2], lo8[2];
    #pragma unroll
    for (int o = 0; o < 16; ++o) {
        unsigned short h = f2bf(hn[o]);
        hi8[o >> 3][o & 7] = (short)h;
        lo8[o >> 3][o & 7] = (short)f2bf(hn[o] - bf2f(h));
    }
    *(short8*)(hHi + (size_t)j * 16)     = hi8[0];
    *(short8*)(hHi + (size_t)j * 16 + 8) = hi8[1];
    *(short8*)(hLo + (size_t)j * 16)     = lo8[0];
    *(short8*)(hLo + (size_t)j * 16 + 8) = lo8[1];
}

// ---------------- MFMA layer kernel ----------------
// MODE 1: middle layer (skip+=, writes h planes). MODE 2: last (out=skip+s).
template <int MODE>
__global__ __launch_bounds__(256) void layer_mfma(
    const unsigned short* __restrict__ hHi_in,
    const unsigned short* __restrict__ hLo_in,
    unsigned short* __restrict__ hHi_out,
    unsigned short* __restrict__ hLo_out,
    const unsigned short* __restrict__ bfrag_l,  // 3072 ushorts
    const float* __restrict__ fgbias_l,          // 32
    const float* __restrict__ rwp_l,             // 256 (MODE 1)
    const float* __restrict__ rb_l,              // 16  (MODE 1)
    const float* __restrict__ mx_l,              // 16
    float* __restrict__ skip,
    float* __restrict__ out,
    int d)
{
    __shared__ float lds[4 * 32 * 36];
    __shared__ float rwl[256];
    __shared__ float sml[32];   // [0:16) mx, [16:32) rb

    const int td = threadIdx.x;
    // ---- stage small weights in LDS (kills per-lane VMEM in epilogue) ----
    if (MODE == 1) rwl[td & 255] = rwp_l[td & 255];
    if (td < 16) sml[td] = mx_l[td];
    else if (MODE == 1 && td < 32) sml[td] = rb_l[td - 16];
    __syncthreads();

    const int wid  = td >> 6;
    const int lane = td & 63;
    const int r0 = lane & 31;          // tile row (t) AND C col via lane&31
    const int kh = lane >> 5;          // k-half / o-half
    // XCD-chunked swizzle: XCD x = bid&7 owns contiguous chunk (nb/8 blocks)
    const int nb = gridDim.x;
    const int wb = (blockIdx.x & 7) * (nb >> 3) + (blockIdx.x >> 3);
    const int j  = wb * 128 + wid * 32 + r0;
    const int t  = j & (TL - 1);

    short8 zero8;
    #pragma unroll
    for (int e = 0; e < 8; ++e) zero8[e] = 0;

    // ---- A fragments: 3 taps x (hi,lo) ----
    short8 ahi[3], alo[3];
    #pragma unroll
    for (int k = 0; k < 3; ++k) {
        const int off = (k - 2) * d;
        const bool ok = (t + off) >= 0;
        const size_t base = (size_t)(ok ? (j + off) : j) * 16 + kh * 8;
        short8 h = *(const short8*)(hHi_in + base);
        short8 l = *(const short8*)(hLo_in + base);
        if (!ok) { h = zero8; l = zero8; }
        ahi[k] = h; alo[k] = l;
    }

    // ---- conv+gate: 9 MFMAs (lo*lo dropped, ~1e-4 contribution) ----
    const float bias = fgbias_l[r0];
    f32x16 acc;
    #pragma unroll
    for (int i = 0; i < 16; ++i) acc[i] = bias;
    const short8* bf = (const short8*)bfrag_l;   // [(tap*2+p)*64 + lane]
    #pragma unroll
    for (int k = 0; k < 3; ++k) {
        short8 bhi = bf[(k * 2 + 0) * 64 + lane];
        short8 blo = bf[(k * 2 + 1) * 64 + lane];
        acc = __builtin_amdgcn_mfma_f32_32x32x16_bf16(ahi[k], bhi, acc, 0, 0, 0);
        acc = __builtin_amdgcn_mfma_f32_32x32x16_bf16(ahi[k], blo, acc, 0, 0, 0);
        acc = __builtin_amdgcn_mfma_f32_32x32x16_bf16(alo[k], bhi, acc, 0, 0, 0);
    }

    // ---- transpose C (col=lane&31, row=(r&3)+8*(r>>2)+4*kh) via LDS ----
    const int wbase = wid * 32 * 36;
    #pragma unroll
    for (int r = 0; r < 16; ++r) {
        const int row = (r & 3) + 8 * (r >> 2) + 4 * kh;
        lds[wbase + row * 36 + r0] = acc[r];
    }
    const int rbase = wbase + r0 * 36 + kh * 8;
    float4 f0v = *(float4*)&lds[rbase];
    float4 f1v = *(float4*)&lds[rbase + 4];
    float4 g0v = *(float4*)&lds[rbase + 16];
    float4 g1v = *(float4*)&lds[rbase + 20];

    float z8[8];
    z8[0] = softsign_f(f0v.x) * softsign_f(g0v.x);
    z8[1] = softsign_f(f0v.y) * softsign_f(g0v.y);
    z8[2] = softsign_f(f0v.z) * softsign_f(g0v.z);
    z8[3] = softsign_f(f0v.w) * softsign_f(g0v.w);
    z8[4] = softsign_f(f1v.x) * softsign_f(g1v.x);
    z8[5] = softsign_f(f1v.y) * softsign_f(g1v.y);
    z8[6] = softsign_f(f1v.z) * softsign_f(g1v.z);
    z8[7] = softsign_f(f1v.w) * softsign_f(g1v.w);

    // ---- mixer dot (halves combined via shfl_xor 32) ----
    float4 m0 = *(float4*)&sml[kh * 8];
    float4 m1 = *(float4*)&sml[kh * 8 + 4];
    float part = m0.x*z8[0] + m0.y*z8[1] + m0.z*z8[2] + m0.w*z8[3]
               + m1.x*z8[4] + m1.y*z8[5] + m1.z*z8[6] + m1.w*z8[7];
    float tot = part + __shfl_xor(part, 32);

    if (MODE == 2) {
        if (kh == 0) out[j] = skip[j] + tot;
        return;
    }
    if (kh == 0) skip[j] += tot;

    // ---- full z row (other half via shfl_xor 32) ----
    float zf[16];
    #pragma unroll
    for (int jo = 0; jo < 8; ++jo) {
        zf[kh * 8 + jo]       = z8[jo];
        zf[(1 - kh) * 8 + jo] = __shfl_xor(z8[jo], 32);
    }

    // ---- residual: hn = h(t) + rb + z @ rw  (fp32 VALU, weights in LDS) ----
    float hn[8];
    float4 rb0 = *(float4*)&sml[16 + kh * 8];
    float4 rb1 = *(float4*)&sml[16 + kh * 8 + 4];
    hn[0] = bf2f((unsigned short)ahi[2][0]) + bf2f((unsigned short)alo[2][0]) + rb0.x;
    hn[1] = bf2f((unsigned short)ahi[2][1]) + bf2f((unsigned short)alo[2][1]) + rb0.y;
    hn[2] = bf2f((unsigned short)ahi[2][2]) + bf2f((unsigned short)alo[2][2]) + rb0.z;
    hn[3] = bf2f((unsigned short)ahi[2][3]) + bf2f((unsigned short)alo[2][3]) + rb0.w;
    hn[4] = bf2f((unsigned short)ahi[2][4]) + bf2f((unsigned short)alo[2][4]) + rb1.x;
    hn[5] = bf2f((unsigned short)ahi[2][5]) + bf2f((unsigned short)alo[2][5]) + rb1.y;
    hn[6] = bf2f((unsigned short)ahi[2][6]) + bf2f((unsigned short)alo[2][6]) + rb1.z;
    hn[7] = bf2f((unsigned short)ahi[2][7]) + bf2f((unsigned short)alo[2][7]) + rb1.w;
    #pragma unroll 4
    for (int i = 0; i < 16; ++i) {
        const float zi = zf[i];
        float4 wA = *(float4*)&rwl[i * 16 + kh * 8];
        float4 wB = *(float4*)&rwl[i * 16 + kh * 8 + 4];
        hn[0] += wA.x * zi; hn[1] += wA.y * zi;
        hn[2] += wA.z * zi; hn[3] += wA.w * zi;
        hn[4] += wB.x * zi; hn[5] += wB.y * zi;
        hn[6] += wB.z * zi; hn[7] += wB.w * zi;
    }

    // ---- store h as split bf16 planes ----
    short8 hi8, lo8;
    #pragma unroll
    for (int jo = 0; jo < 8; ++jo) {
        unsigned short h = f2bf(hn[jo]);
        hi8[jo] = (short)h;
        lo8[jo] = (short)f2bf(hn[jo] - bf2f(h));
    }
    *(short8*)(hHi_out + (size_t)j * 16 + kh * 8) = hi8;
    *(short8*)(hLo_out + (size_t)j * 16 + kh * 8) = lo8;
}

extern "C" void kernel_launch(void* const* d_in, const int* in_sizes, int n_in,
                              void* d_out, int out_size, void* d_ws, size_t ws_size,
                              hipStream_t stream) {
    const float* x       = (const float*)d_in[0];
    const float* start_w = (const float*)d_in[1];
    const float* conv_w  = (const float*)d_in[2];
    const float* conv_b  = (const float*)d_in[3];
    const float* gate_w  = (const float*)d_in[4];
    const float* gate_b  = (const float*)d_in[5];
    const float* res_w   = (const float*)d_in[6];
    const float* res_b   = (const float*)d_in[7];
    const float* mixer_w = (const float*)d_in[8];
    float* out = (float*)d_out;

    float* ws = (float*)d_ws;
    unsigned short* bfrag = (unsigned short*)ws;            // 55296 ushorts
    float* fgbias = ws + 27648;                             // 576
    float* rwp    = fgbias + 576;                           // 4352
    float* e0f    = rwp + 4352;                             // 48
    float* e0g    = e0f + 48;                               // 48
    unsigned short* hHiA = (unsigned short*)(e0g + 48);     // 4 planes x 8MB
    unsigned short* hLoA = hHiA + 4194304;
    unsigned short* hHiB = hLoA + 4194304;
    unsigned short* hLoB = hHiB + 4194304;
    float* skip = (float*)(hLoB + 4194304);                 // 262144
    (void)ws_size; (void)in_sizes; (void)n_in; (void)out_size;

    pack_kernel<<<236, 256, 0, stream>>>(start_w, conv_w, gate_w, res_w,
                                         conv_b, gate_b,
                                         bfrag, fgbias, rwp, e0f, e0g);

    static const int dil[18] = {1,2,4,8,16,32,64,128,256,1,2,4,8,16,32,64,128,256};

    // layer 0 (VALU, writes plane set A + skip)
    layer0_kernel<<<NTOT / 256, 256, 0, stream>>>(
        x, start_w, e0f, conv_b, e0g, gate_b,
        rwp, res_b, mixer_w, hHiA, hLoA, skip);

    unsigned short* hi[2] = {hHiA, hHiB};
    unsigned short* lo[2] = {hLoA, hLoB};
    const int nblk = NTOT / 128;   // 2048 blocks, 128 rows each

    for (int li = 1; li < 17; ++li) {
        const int pin = (li - 1) & 1, pout = li & 1;
        layer_mfma<1><<<nblk, 256, 0, stream>>>(
            hi[pin], lo[pin], hi[pout], lo[pout],
            bfrag + li * 3072, fgbias + li * 32,
            rwp + li * 256, res_b + li * 16, mixer_w + li * 16,
            skip, nullptr, dil[li]);
    }

    // layer 17: out = skip + contribution
    layer_mfma<2><<<nblk, 256, 0, stream>>>(
        hi[0], lo[0], nullptr, nullptr,
        bfrag + 17 * 3072, fgbias + 17 * 32,
        nullptr, nullptr, mixer_w + 17 * 16,
        skip, out, dil[17]);
}